// Round 1
// baseline (23.986 us; speedup 1.0000x reference)
//
#include <hip/hip_runtime.h>
#include <math.h>

#define EPS 1e-12f

constexpr int R = 8;
constexpr int N = 1024;
constexpr int F = 256;
constexpr int NPAIR = 64;   // R*R

// Kernel 1: one block per row-index n. Load A[8][256], B[8][256] into LDS,
// compute the 16 row norms in-block, then all 64 pair dot products.
__global__ __launch_bounds__(256) void dot_kernel(const float* __restrict__ gfa,
                                                  const float* __restrict__ gfb,
                                                  float* __restrict__ v) {
    const int n = blockIdx.x;     // 0..N-1
    const int t = threadIdx.x;    // 0..255
    __shared__ float As[8][256];
    __shared__ float Bs[8][256];
    __shared__ float invn[16];    // [0..7]=A rows, [8..15]=B rows

    #pragma unroll
    for (int r = 0; r < 8; ++r) {
        As[r][t] = gfa[((size_t)r * N + n) * F + t];
        Bs[r][t] = gfb[((size_t)r * N + n) * F + t];
    }
    __syncthreads();

    // Row norms: wave w handles A rows {2w,2w+1} and B rows {2w,2w+1}.
    const int wave = t >> 6, lane = t & 63;
    #pragma unroll
    for (int rr = 0; rr < 2; ++rr) {
        const int row = wave * 2 + rr;
        float sa = 0.f, sb = 0.f;
        #pragma unroll
        for (int j = 0; j < 4; ++j) {
            float xa = As[row][lane + 64 * j];
            float xb = Bs[row][lane + 64 * j];
            sa += xa * xa;
            sb += xb * xb;
        }
        #pragma unroll
        for (int off = 32; off; off >>= 1) {
            sa += __shfl_down(sa, off);
            sb += __shfl_down(sb, off);
        }
        if (lane == 0) {
            invn[row]     = 1.f / fmaxf(sqrtf(sa), EPS);
            invn[8 + row] = 1.f / fmaxf(sqrtf(sb), EPS);
        }
    }
    __syncthreads();

    // Dot phase: 4 threads per pair, each sums 64 elements.
    const int pair = t >> 2;          // 0..63
    const int q = t & 3;              // quarter of the F dimension
    const int ra = pair >> 3, rb = pair & 7;
    const int base = q * 64;
    float acc = 0.f;
    #pragma unroll
    for (int k = 0; k < 64; ++k) {
        const int col = base + ((k + lane) & 63);   // rotate to spread banks
        acc += As[ra][col] * Bs[rb][col];
    }
    acc += __shfl_down(acc, 2);
    acc += __shfl_down(acc, 1);
    if (q == 0) {
        v[(size_t)pair * N + n] = acc * invn[ra] * invn[8 + rb];
    }
}

// Kernel 2: one 1024-thread block per (ra,rb) pair.
// Bitonic-sort v ascending in LDS, then fused reductions.
__global__ __launch_bounds__(1024) void pair_kernel(const float* __restrict__ v,
                                                    const float* __restrict__ ca,
                                                    const float* __restrict__ cb,
                                                    float* __restrict__ sims) {
    const int p = blockIdx.x;        // 0..63
    const int ra = p >> 3, rb = p & 7;
    const int i = threadIdx.x;       // 0..1023
    __shared__ float s[N];
    __shared__ float rbuf[6][16];

    s[i] = v[(size_t)p * N + i];
    __syncthreads();

    // Standard bitonic sort, ascending.
    for (int k = 2; k <= N; k <<= 1) {
        for (int j = k >> 1; j > 0; j >>= 1) {
            const int ixj = i ^ j;
            if (ixj > i) {
                const float a = s[i], b = s[ixj];
                const bool up = ((i & k) == 0);
                if ((a > b) == up) { s[i] = b; s[ixj] = a; }
            }
            __syncthreads();
        }
    }

    // Descending position i -> s[N-1-i].  vmin = s[0].
    const float vmin = s[0];
    const float u = s[N - 1 - i] - vmin;         // sorted weight at position i
    const float ex = ca[((size_t)ra * N + i) * 2 + 0] - cb[((size_t)rb * N + i) * 2 + 0];
    const float ey = ca[((size_t)ra * N + i) * 2 + 1] - cb[((size_t)rb * N + i) * 2 + 1];
    const float elen2 = ex * ex + ey * ey;
    const float t16 = (i >= N - 16) ? s[i] : 0.f;  // top-16 values

    float vals[6] = { u, u * u, u * elen2, u * ex, u * ey, t16 };

    const int wave = i >> 6, lane = i & 63;
    #pragma unroll
    for (int m = 0; m < 6; ++m) {
        float x = vals[m];
        #pragma unroll
        for (int off = 32; off; off >>= 1) x += __shfl_down(x, off);
        if (lane == 0) rbuf[m][wave] = x;
    }
    __syncthreads();

    if (i == 0) {
        float su = 0.f, u2 = 0.f, A = 0.f, Bx = 0.f, By = 0.f, T = 0.f;
        #pragma unroll
        for (int w = 0; w < 16; ++w) {
            su += rbuf[0][w]; u2 += rbuf[1][w]; A += rbuf[2][w];
            Bx += rbuf[3][w]; By += rbuf[4][w]; T += rbuf[5][w];
        }
        const float sim_feat = T * (1.f / 16.f);
        const float denom = (float)N * (float)N * fmaxf(u2, EPS);
        const float dis_loc = (2.f * su * A - 2.f * (Bx * Bx + By * By)) / denom;
        sims[p] = sim_feat - dis_loc;
    }
}

// Kernel 3: max over the 64 pair scores.
__global__ __launch_bounds__(64) void max_kernel(const float* __restrict__ sims,
                                                 float* __restrict__ out) {
    const int i = threadIdx.x;   // 0..63
    float x = sims[i];
    #pragma unroll
    for (int off = 32; off; off >>= 1) x = fmaxf(x, __shfl_down(x, off));
    if (i == 0) out[0] = x;
}

extern "C" void kernel_launch(void* const* d_in, const int* in_sizes, int n_in,
                              void* d_out, int out_size, void* d_ws, size_t ws_size,
                              hipStream_t stream) {
    const float* gfa = (const float*)d_in[0];  // (8,1024,256)
    const float* ca  = (const float*)d_in[1];  // (8,1024,2)
    const float* gfb = (const float*)d_in[2];  // (8,1024,256)
    const float* cb  = (const float*)d_in[3];  // (8,1024,2)
    float* out = (float*)d_out;

    float* v    = (float*)d_ws;                // 64*1024 floats
    float* sims = v + (size_t)NPAIR * N;       // 64 floats

    dot_kernel<<<N, 256, 0, stream>>>(gfa, gfb, v);
    pair_kernel<<<NPAIR, 1024, 0, stream>>>(v, ca, cb, sims);
    max_kernel<<<1, 64, 0, stream>>>(sims, out);
}

// Round 2
// 23.219 us; speedup vs baseline: 1.0331x; 1.0331x over previous
//
#include <hip/hip_runtime.h>
#include <math.h>

#define EPS 1e-12f

constexpr int N = 1024;
constexpr int F = 256;
constexpr int NPAIR = 64;   // R*R

__device__ inline void atomicMaxFloat(float* addr, float val) {
    unsigned int* ua = (unsigned int*)addr;
    unsigned int old = __float_as_uint(*addr);
    while (__uint_as_float(old) < val) {
        unsigned int assumed = old;
        old = atomicCAS(ua, assumed, __float_as_uint(val));
        if (old == assumed) break;
    }
}

// Kernel 1: one block per row-index n (1024 blocks x 256 threads = 4 waves).
// Stage 16 rows (8 A + 8 B, 256 f32 each) in LDS as float4, compute the 16
// row norms, then all 64 normalized dots via register-held B rows + shuffle
// reductions. Also initializes out[0] = -inf for kernel 2's atomicMax.
__global__ __launch_bounds__(256) void dot_kernel(const float* __restrict__ gfa,
                                                  const float* __restrict__ gfb,
                                                  float* __restrict__ v,
                                                  float* __restrict__ out) {
    const int n = blockIdx.x;     // 0..N-1
    const int t = threadIdx.x;    // 0..255
    __shared__ float4 rows[16][64];   // rows 0..7 = A, 8..15 = B
    __shared__ float invn[16];

    if (n == 0 && t == 0) out[0] = -INFINITY;

    // Load: each wave fetches one full 1 KB row per rep (perfectly coalesced).
    #pragma unroll
    for (int rep = 0; rep < 4; ++rep) {
        const int idx = rep * 256 + t;      // 0..1023
        const int row = idx >> 6;           // 0..15
        const int c4  = idx & 63;
        const float* src = (row < 8) ? gfa + ((size_t)row * N + n) * F
                                     : gfb + ((size_t)(row - 8) * N + n) * F;
        rows[row][c4] = ((const float4*)src)[c4];
    }
    __syncthreads();

    const int wave = t >> 6, lane = t & 63;

    // Norms: wave w handles rows 4w..4w+3.
    #pragma unroll
    for (int rr = 0; rr < 4; ++rr) {
        const int row = wave * 4 + rr;
        const float4 a = rows[row][lane];
        float ss = a.x * a.x + a.y * a.y + a.z * a.z + a.w * a.w;
        #pragma unroll
        for (int off = 32; off; off >>= 1) ss += __shfl_down(ss, off);
        if (lane == 0) invn[row] = 1.f / fmaxf(sqrtf(ss), EPS);
    }
    __syncthreads();

    // Dots: wave w handles ra in {2w, 2w+1} x rb in 0..7 (16 pairs).
    float4 b[8];
    #pragma unroll
    for (int rb = 0; rb < 8; ++rb) b[rb] = rows[8 + rb][lane];

    #pragma unroll
    for (int rr = 0; rr < 2; ++rr) {
        const int ra = wave * 2 + rr;
        const float4 a = rows[ra][lane];
        #pragma unroll
        for (int rb = 0; rb < 8; ++rb) {
            float d = a.x * b[rb].x + a.y * b[rb].y + a.z * b[rb].z + a.w * b[rb].w;
            #pragma unroll
            for (int off = 32; off; off >>= 1) d += __shfl_down(d, off);
            if (lane == 0)
                v[(size_t)(ra * 8 + rb) * N + n] = d * invn[ra] * invn[8 + rb];
        }
    }
}

// Kernel 2: one 1024-thread block per (ra,rb) pair. Hybrid bitonic sort:
// partner distance < 64 -> __shfl_xor (registers, no barrier); >= 64 -> LDS.
// Then fused reductions + CAS float atomicMax into out[0].
__global__ __launch_bounds__(1024) void pair_kernel(const float* __restrict__ v,
                                                    const float* __restrict__ ca,
                                                    const float* __restrict__ cb,
                                                    float* __restrict__ out) {
    const int p = blockIdx.x;        // 0..63
    const int ra = p >> 3, rb = p & 7;
    const int i = threadIdx.x;       // 0..1023
    __shared__ float s[N];
    __shared__ float rbuf[16][6];

    float x = v[(size_t)p * N + i];

    // Bitonic sort ascending; k=2..64: pure in-register shuffle phases.
    #pragma unroll
    for (int k = 2; k <= 64; k <<= 1) {
        #pragma unroll
        for (int j = k >> 1; j >= 1; j >>= 1) {
            const float y = __shfl_xor(x, j);
            const bool keepMin = (((i & j) == 0) == ((i & k) == 0));
            x = keepMin ? fminf(x, y) : fmaxf(x, y);
        }
    }
    // k=128..1024: j>=64 via LDS (2 barriers each), j<=32 via shuffle.
    #pragma unroll
    for (int k = 128; k <= 1024; k <<= 1) {
        for (int j = k >> 1; j >= 64; j >>= 1) {
            s[i] = x;
            __syncthreads();
            const float y = s[i ^ j];
            const bool keepMin = (((i & j) == 0) == ((i & k) == 0));
            x = keepMin ? fminf(x, y) : fmaxf(x, y);
            __syncthreads();
        }
        #pragma unroll
        for (int j = 32; j >= 1; j >>= 1) {
            const float y = __shfl_xor(x, j);
            const bool keepMin = (((i & j) == 0) == ((i & k) == 0));
            x = keepMin ? fminf(x, y) : fmaxf(x, y);
        }
    }
    s[i] = x;                 // s = v sorted ascending
    __syncthreads();

    const float vmin = s[0];
    const float u = s[N - 1 - i] - vmin;          // descending position i
    const float t16 = (i >= N - 16) ? x : 0.f;    // top-16 values

    const float2 cA = ((const float2*)ca)[(size_t)ra * N + i];
    const float2 cB = ((const float2*)cb)[(size_t)rb * N + i];
    const float ex = cA.x - cB.x;
    const float ey = cA.y - cB.y;
    const float e2 = ex * ex + ey * ey;

    float vals[6] = { u, u * u, u * e2, u * ex, u * ey, t16 };

    const int wave = i >> 6, lane = i & 63;
    #pragma unroll
    for (int m = 0; m < 6; ++m) {
        float r = vals[m];
        #pragma unroll
        for (int off = 32; off; off >>= 1) r += __shfl_down(r, off);
        if (lane == 0) rbuf[wave][m] = r;
    }
    __syncthreads();

    if (wave == 0) {
        float acc[6];
        #pragma unroll
        for (int m = 0; m < 6; ++m) {
            float r = (lane < 16) ? rbuf[lane][m] : 0.f;
            r += __shfl_down(r, 8);
            r += __shfl_down(r, 4);
            r += __shfl_down(r, 2);
            r += __shfl_down(r, 1);
            acc[m] = r;
        }
        if (lane == 0) {
            const float Su = acc[0], U2 = acc[1], A = acc[2];
            const float Bx = acc[3], By = acc[4], T = acc[5];
            const float sim_feat = T * (1.f / 16.f);
            const float denom = (float)N * (float)N * fmaxf(U2, EPS);
            const float dis_loc = (2.f * Su * A - 2.f * (Bx * Bx + By * By)) / denom;
            atomicMaxFloat(out, sim_feat - dis_loc);
        }
    }
}

extern "C" void kernel_launch(void* const* d_in, const int* in_sizes, int n_in,
                              void* d_out, int out_size, void* d_ws, size_t ws_size,
                              hipStream_t stream) {
    const float* gfa = (const float*)d_in[0];  // (8,1024,256)
    const float* ca  = (const float*)d_in[1];  // (8,1024,2)
    const float* gfb = (const float*)d_in[2];  // (8,1024,256)
    const float* cb  = (const float*)d_in[3];  // (8,1024,2)
    float* out = (float*)d_out;

    float* v = (float*)d_ws;                   // 64*1024 floats

    dot_kernel<<<N, 256, 0, stream>>>(gfa, gfb, v, out);
    pair_kernel<<<NPAIR, 1024, 0, stream>>>(v, ca, cb, out);
}